// Round 9
// baseline (697.931 us; speedup 1.0000x reference)
//
#include <hip/hip_runtime.h>
#include <stdint.h>

namespace {

constexpr int kB      = 8;
constexpr int kT      = 4096;
constexpr int kC4     = 256;            // 1024 f32 channels as float4
constexpr int kSegLen = 64;
constexpr int kNSeg   = kT / kSegLen;   // 64 segments per batch chain
constexpr int kTiles  = kB * kNSeg;     // 512 blocks
constexpr int kSub    = 16;             // timesteps per thread (4 quarters x 16)

// d_ws layout: [0] ticket u32 | [256] flags u32[512] | [8192] values float4[512][256]
constexpr size_t kFlagOff = 256;
constexpr size_t kValOff  = 8192;
constexpr size_t kClear   = 4096;       // bytes to zero each launch (ticket+flags)

typedef float f4 __attribute__((ext_vector_type(4)));

__global__ __launch_bounds__(1024, 8) void fused_scan(const float4* __restrict__ x,
                                                      float4* __restrict__ out,
                                                      uint32_t* __restrict__ ticket,
                                                      uint32_t* __restrict__ flags,
                                                      float4* __restrict__ vals) {
    __shared__ float4   s_sums[4][kC4];   // quarter sums, 16 KB
    __shared__ float4   s_off[kC4];       // chain offset broadcast, 4 KB
    __shared__ uint32_t s_tile;

    if (threadIdx.x == 0) s_tile = atomicAdd(ticket, 1u);
    __syncthreads();
    const uint32_t tile = s_tile;
    const int b   = (int)(tile & 7u);     // interleave the 8 batch chains
    const int seg = (int)(tile >> 3);     // preds have strictly lower tickets
    const int c4  = (int)(threadIdx.x & 255u);
    const int q   = (int)(threadIdx.x >> 8);

    // Phase 1: each thread sums its 16 timesteps (coalesced; x becomes L3-hot).
    const size_t base = ((size_t)(b * kT + seg * kSegLen + q * kSub)) * kC4 + c4;
    const float4* p = x + base;
    float sx = 0.f, sy = 0.f, sz = 0.f, sw = 0.f;
#pragma unroll 4
    for (int i = 0; i < kSub; ++i) {
        const float4 v = p[(size_t)i * kC4];
        sx += v.x; sy += v.y; sz += v.z; sw += v.w;
    }
    s_sums[q][c4] = make_float4(sx, sy, sz, sw);
    __syncthreads();

    // Exclusive intra-tile offset over quarters (<=3 LDS reads, 2-way alias free).
    float px = 0.f, py = 0.f, pz = 0.f, pw = 0.f;
    for (int qq = 0; qq < q; ++qq) {
        const float4 s = s_sums[qq][c4];
        px += s.x; py += s.y; pz += s.z; pw += s.w;
    }

    // Publish tile aggregate: plain value stores, fence, then one released flag.
    if (q == 3) {
        vals[((size_t)tile << 8) + c4] =
            make_float4(px + sx, py + sy, pz + sz, pw + sw);
        __threadfence();                  // push value stores to device scope
    }
    __syncthreads();
    if (threadIdx.x == 0)
        __hip_atomic_store(&flags[tile], 1u, __ATOMIC_RELEASE,
                           __HIP_MEMORY_SCOPE_AGENT);

    // Phase 2 (q==0 quarter): windowed forward lookback. Spin on 4-byte flags
    // (broadcast load), then bulk-read the 4 KB value rows exactly once.
    if (q == 0) {
        float ox = 0.f, oy = 0.f, oz = 0.f, ow = 0.f;
        for (int s = 0; s < seg; s += 4) {
            const int n = (seg - s < 4) ? (seg - s) : 4;
            for (;;) {
                uint32_t ok = 1u;
#pragma unroll
                for (int k = 0; k < 4; ++k) {
                    if (k < n) {
                        const uint32_t pt = (uint32_t)(((s + k) << 3) | b);
                        ok &= __hip_atomic_load(&flags[pt], __ATOMIC_ACQUIRE,
                                                __HIP_MEMORY_SCOPE_AGENT);
                    }
                }
                if (ok) break;
                __builtin_amdgcn_s_sleep(2);
            }
#pragma unroll
            for (int k = 0; k < 4; ++k) {
                if (k < n) {
                    const uint32_t pt = (uint32_t)(((s + k) << 3) | b);
                    const float4 v = vals[((size_t)pt << 8) + c4];
                    ox += v.x; oy += v.y; oz += v.z; ow += v.w;
                }
            }
        }
        s_off[c4] = make_float4(ox, oy, oz, ow);
    }
    __syncthreads();

    // Phase 3: running prefix from (chain offset + quarter offset); re-read x
    // (L3-hot), nontemporal store of the mean.
    const float4 co = s_off[c4];
    float ox = co.x + px, oy = co.y + py, oz = co.z + pz, ow = co.w + pw;
    f4* o = (f4*)(out + base);
    const int t0 = seg * kSegLen + q * kSub;
#pragma unroll 4
    for (int i = 0; i < kSub; ++i) {
        const float4 v = p[(size_t)i * kC4];
        ox += v.x; oy += v.y; oz += v.z; ow += v.w;
        const float inv = __builtin_amdgcn_rcpf((float)(t0 + i + 1));
        f4 r;
        r.x = ox * inv; r.y = oy * inv; r.z = oz * inv; r.w = ow * inv;
        __builtin_nontemporal_store(r, o + (size_t)i * kC4);
    }
}

}  // namespace

extern "C" void kernel_launch(void* const* d_in, const int* in_sizes, int n_in,
                              void* d_out, int out_size, void* d_ws, size_t ws_size,
                              hipStream_t stream) {
    const float4* x = (const float4*)d_in[0];
    float4* out     = (float4*)d_out;
    uint32_t* ctr   = (uint32_t*)d_ws;
    uint32_t* flags = (uint32_t*)((char*)d_ws + kFlagOff);
    float4*   vals  = (float4*)((char*)d_ws + kValOff);
    // Clear ticket + flags only (4 KB — instant, graph-capturable).
    (void)hipMemsetAsync(d_ws, 0, kClear, stream);
    fused_scan<<<kTiles, 1024, 0, stream>>>(x, out, ctr, flags, vals);
}

// Round 11
// 126.986 us; speedup vs baseline: 5.4961x; 5.4961x over previous
//
#include <hip/hip_runtime.h>
#include <hip/hip_cooperative_groups.h>
#include <stdint.h>

namespace cg = cooperative_groups;

namespace {
constexpr int kB      = 8;
constexpr int kT      = 4096;
constexpr int kC4     = 256;            // 1024 f32 channels as float4
constexpr int kSegLen = 64;
constexpr int kNSeg   = kT / kSegLen;   // 64 segments per batch chain
constexpr int kTiles  = kB * kNSeg;     // 512 blocks
constexpr size_t kPartF4 = (size_t)kTiles * kC4;   // 2 MiB table

typedef float f4 __attribute__((ext_vector_type(4)));
}  // namespace

// ---------------- cooperative single-pass path ----------------
// 512 blocks x 256 threads (4 waves) — ample co-residency margin (needs 2/CU,
// occupancy bound is ~8/CU at this VGPR/LDS footprint).
__global__ __launch_bounds__(256) void coop_scan(const float4* __restrict__ x,
                                                 float4* __restrict__ out,
                                                 float4* __restrict__ vals) {
    const int tile = (int)blockIdx.x;
    const int b    = tile >> 6;           // kNSeg == 64
    const int seg  = tile & (kNSeg - 1);
    const int c4   = (int)threadIdx.x;

    // Phase 1: full-segment column sum (64 coalesced loads; x becomes L3-hot).
    const size_t base = ((size_t)(b * kT + seg * kSegLen)) * kC4 + c4;
    const float4* p = x + base;
    float sx = 0.f, sy = 0.f, sz = 0.f, sw = 0.f;
#pragma unroll 8
    for (int i = 0; i < kSegLen; ++i) {
        const float4 v = p[(size_t)i * kC4];
        sx += v.x; sy += v.y; sz += v.z; sw += v.w;
    }
    vals[((size_t)tile << 8) + c4] = make_float4(sx, sy, sz, sw);

    cg::this_grid().sync();

    // Phase 2: chain offset = sum of predecessor aggregates (coalesced, L2-hot).
    float ox = 0.f, oy = 0.f, oz = 0.f, ow = 0.f;
#pragma unroll 4
    for (int s = 0; s < seg; ++s) {
        const float4 v = vals[((size_t)((b << 6) | s) << 8) + c4];
        ox += v.x; oy += v.y; oz += v.z; ow += v.w;
    }

    // Phase 3: re-read segment (L3-hot), running prefix, nt-store the mean.
    f4* o = (f4*)(out + base);
    const int t0 = seg * kSegLen;
#pragma unroll 4
    for (int i = 0; i < kSegLen; ++i) {
        const float4 v = p[(size_t)i * kC4];
        ox += v.x; oy += v.y; oz += v.z; ow += v.w;
        const float inv = __builtin_amdgcn_rcpf((float)(t0 + i + 1));
        f4 r;
        r.x = ox * inv; r.y = oy * inv; r.z = oz * inv; r.w = ow * inv;
        __builtin_nontemporal_store(r, o + (size_t)i * kC4);
    }
}

// ---------------- fallback: proven R3 three-kernel path ----------------
__global__ __launch_bounds__(256) void seg_sum_kernel(const float4* __restrict__ x,
                                                      float4* __restrict__ part) {
    const int tid = blockIdx.x * 256 + threadIdx.x;
    const int c4  = tid & (kC4 - 1);
    const int seg = (tid >> 8) & (kNSeg - 1);
    const int b   = tid >> 14;
    const float4* p = x + ((size_t)(b * kT + seg * kSegLen)) * kC4 + c4;
    float sx = 0.f, sy = 0.f, sz = 0.f, sw = 0.f;
#pragma unroll 8
    for (int i = 0; i < kSegLen; ++i) {
        const float4 v = p[(size_t)i * kC4];
        sx += v.x; sy += v.y; sz += v.z; sw += v.w;
    }
    part[tid] = make_float4(sx, sy, sz, sw);
}

__global__ __launch_bounds__(64) void seg_prefix_kernel(const float4* __restrict__ part,
                                                        float4* __restrict__ excl) {
    const int col = blockIdx.x * 64 + threadIdx.x;         // 2048 (b,c4) columns
    const int c4  = col & (kC4 - 1);
    const int b   = col >> 8;
    const float4* p = part + (size_t)b * kNSeg * kC4 + c4;
    float4*       e = excl + (size_t)b * kNSeg * kC4 + c4;
    float rx = 0.f, ry = 0.f, rz = 0.f, rw = 0.f;
#pragma unroll 8
    for (int s = 0; s < kNSeg; ++s) {
        const float4 v = p[(size_t)s * kC4];
        e[(size_t)s * kC4] = make_float4(rx, ry, rz, rw);
        rx += v.x; ry += v.y; rz += v.z; rw += v.w;
    }
}

__global__ __launch_bounds__(256) void scan_write_kernel(const float4* __restrict__ x,
                                                         const float4* __restrict__ excl,
                                                         float4* __restrict__ out) {
    const int tid = blockIdx.x * 256 + threadIdx.x;
    const int c4  = tid & (kC4 - 1);
    const int seg = (tid >> 8) & (kNSeg - 1);
    const int b   = tid >> 14;
    const float4 o4 = excl[tid];
    float ox = o4.x, oy = o4.y, oz = o4.z, ow = o4.w;
    const size_t base = ((size_t)(b * kT + seg * kSegLen)) * kC4 + c4;
    const float4* p = x + base;
    f4* o = (f4*)(out + base);
    const int t0 = seg * kSegLen;
#pragma unroll 4
    for (int i = 0; i < kSegLen; ++i) {
        const float4 v = p[(size_t)i * kC4];
        ox += v.x; oy += v.y; oz += v.z; ow += v.w;
        const float inv = __builtin_amdgcn_rcpf((float)(t0 + i + 1));
        f4 r;
        r.x = ox * inv; r.y = oy * inv; r.z = oz * inv; r.w = ow * inv;
        __builtin_nontemporal_store(r, o + (size_t)i * kC4);
    }
}

extern "C" void kernel_launch(void* const* d_in, const int* in_sizes, int n_in,
                              void* d_out, int out_size, void* d_ws, size_t ws_size,
                              hipStream_t stream) {
    const float4* x = (const float4*)d_in[0];
    float4* out     = (float4*)d_out;
    float4* vals    = (float4*)d_ws;                       // 2 MiB
    void* args[] = { (void*)&x, (void*)&out, (void*)&vals };
    hipError_t err = hipLaunchCooperativeKernel((const void*)coop_scan, dim3(kTiles),
                                                dim3(256), args, 0, stream);
    if (err != hipSuccess) {
        // Deterministic capability-based fallback: proven 3-kernel path.
        float4* part = (float4*)d_ws;
        float4* excl = part + kPartF4;
        constexpr int total = kB * kNSeg * kC4;
        seg_sum_kernel<<<total / 256, 256, 0, stream>>>(x, part);
        seg_prefix_kernel<<<kB * kC4 / 64, 64, 0, stream>>>(part, excl);
        scan_write_kernel<<<total / 256, 256, 0, stream>>>(x, excl, out);
    }
}